// Round 9
// baseline (146.838 us; speedup 1.0000x reference)
//
#include <hip/hip_runtime.h>

#define B_ 8
#define N_ 20000
#define M_ 1024
#define C_ 128
#define S_ 64
#define NCH_ 131     // 3 + C
#define CHUNK_ 1024  // points per block-iteration (4 waves x 256)
#define NCHK_ ((N_ + CHUNK_ - 1) / CHUNK_)   // 20 chunks
#define CF4_ ((CHUNK_ * 3) / 4)              // 768 float4 per chunk
#define XYZF4MAX_ ((B_ * N_ * 3) / 4 - 1)    // last valid float4 index in xyz

typedef float  vf4 __attribute__((ext_vector_type(4)));  // nontemporal-compatible 16B

// ---- K1: ball query; coalesced LDS staging + interleaved-lane evaluation ---
__global__ __launch_bounds__(256) void query_kernel(
    const float* __restrict__ xyz,       // (B, N, 3)
    const float* __restrict__ new_xyz,   // (B, M, 3)
    float* __restrict__ out,
    int* __restrict__ iws)               // (B, M, S) int scratch
{
    const int tid  = threadIdx.x;
    const int wid  = tid >> 6;
    const int lane = tid & 63;
    const int bm   = blockIdx.x;         // one block per center
    const int b    = bm >> 10;
    const int m    = bm & (M_ - 1);

    __shared__ __align__(16) float s_pts[2][CHUNK_ * 3];  // 2 x 12 KB
    __shared__ int s_idx[S_];
    __shared__ int s_tot[2][4];          // per-wave totals, double-buffered

    const float cx = new_xyz[bm * 3 + 0];
    const float cy = new_xyz[bm * 3 + 1];
    const float cz = new_xyz[bm * 3 + 2];
    const float r2 = (float)(0.3 * 0.3);
    const unsigned long long below = (1ull << lane) - 1ull;

    const float4* g4 = (const float4*)xyz;
    const int batch_f4 = b * ((N_ * 3) / 4);   // 15000 per batch

    // stage chunk T (coalesced, line-perfect): 3 float4 per thread
#define STAGE_CHUNK(T, DST) do {                                              \
        const int cb4 = batch_f4 + (T) * CF4_;                                \
        float4* d4 = (float4*)(DST);                                          \
        _Pragma("unroll")                                                     \
        for (int k = 0; k < CF4_ / 256; ++k) {                                \
            int gi = cb4 + k * 256 + tid;                                     \
            gi = gi < XYZF4MAX_ ? gi : XYZF4MAX_;   /* tail clamp (dup data) */ \
            d4[k * 256 + tid] = g4[gi];                                       \
        }                                                                     \
    } while (0)

    int cnt = 0;
    int t = 0, par = 0;

    STAGE_CHUNK(0, s_pts[0]);
    __syncthreads();

    for (;;) {
        const float* cur = s_pts[par];
        if (t + 1 < NCHK_) STAGE_CHUNK(t + 1, s_pts[par ^ 1]);

        // evaluate: lane owns points 64j+lane of this wave's 256-pt slice
        unsigned vbits = 0;
        int tot = 0;
#pragma unroll
        for (int j = 0; j < 4; ++j) {
            const int pl = (wid << 8) + (j << 6) + lane;   // point in chunk
            const int n  = t * CHUNK_ + pl;
            bool valid = false;
            if (n < N_) {
                const float* pp = cur + 3 * pl;    // lane stride 12B: 2-way, free
                // match numpy f32 rounding exactly: no FMA contraction
                const float dx = __fadd_rn(pp[0], -cx);
                const float dy = __fadd_rn(pp[1], -cy);
                const float dz = __fadd_rn(pp[2], -cz);
                const float d2 = __fadd_rn(
                    __fadd_rn(__fmul_rn(dx, dx), __fmul_rn(dy, dy)),
                    __fmul_rn(dz, dz));
                valid = d2 < r2;
            }
            const unsigned long long mk = __ballot(valid);
            if (valid) vbits |= (1u << j);
            tot += __popcll(mk);
        }
        if (lane == 0) s_tot[par][wid] = tot;
        __syncthreads();   // s_tot visible + next-chunk staging complete

        int off = cnt;
#pragma unroll
        for (int w = 0; w < 4; ++w) { if (w < wid) off += s_tot[par][w]; }

        // ordered scatter: group-major (j ascending), lane-ascending within group
        int jbase = off;
#pragma unroll
        for (int j = 0; j < 4; ++j) {
            const unsigned long long mk = __ballot((vbits >> j) & 1u);
            if ((vbits >> j) & 1u) {
                const int pos = jbase + __popcll(mk & below);
                if (pos < S_) s_idx[pos] = t * CHUNK_ + (wid << 8) + (j << 6) + lane;
            }
            jbase += __popcll(mk);
        }
        cnt += s_tot[par][0] + s_tot[par][1] + s_tot[par][2] + s_tot[par][3];

        ++t;
        par ^= 1;
        if (cnt >= S_ || t >= NCHK_) break;
    }
#undef STAGE_CHUNK

    __syncthreads();   // all s_idx writes visible block-wide
    {
        const int c = cnt < S_ ? cnt : S_;
        const int first = (c > 0) ? s_idx[0] : 0;
        if (tid >= c && tid < S_) s_idx[tid] = first;
    }
    __syncthreads();

    const float* xb = xyz + (size_t)b * N_ * 3;
    if (tid < S_) {
        const int n = s_idx[tid];
        // idx outputs (float copy in d_out, int copy for K2 -- keep iws L2-hot)
        float* out_idx = out + (size_t)B_ * NCH_ * M_ * S_;
        __builtin_nontemporal_store((float)n, &out_idx[(size_t)bm * S_ + tid]);
        iws[(size_t)bm * S_ + tid] = n;
    }
    if (tid < 3 * S_) {
        const int ch = tid >> 6;             // 0..2
        const int s  = tid & 63;
        const int n  = s_idx[s];
        const float cc = new_xyz[bm * 3 + ch];
        const float v = (xb[n * 3 + ch] - cc) / 0.3f;
        __builtin_nontemporal_store(v,
            &out[(((size_t)b * NCH_ + ch) * M_ + m) * S_ + s]);
    }
}

// ---- K2: per (b,ch) block -- stage 80KB channel slice in LDS, gather-write -
__global__ __launch_bounds__(256) void group_feat_kernel(
    const float* __restrict__ features,  // (B, C, N)
    const int* __restrict__ iws,         // (B, M, S)
    float* __restrict__ out)
{
    // b = blockIdx & 7: round-robin dispatch pins each batch to one XCD,
    // keeping that batch's idx slice (256 KB) L2-resident.
    const int b  = blockIdx.x & 7;
    const int ch = blockIdx.x >> 3;

    __shared__ float slice[N_];          // 80000 B (gfx950: >64KB LDS ok)

    const float* fb = features + ((size_t)b * C_ + ch) * N_;
    const vf4* fb4 = (const vf4*)fb;
    vf4* sl4 = (vf4*)slice;
    for (int i = threadIdx.x; i < N_ / 4; i += 256)
        sl4[i] = __builtin_nontemporal_load(&fb4[i]);  // read-once stream
    __syncthreads();

    const int* ib = iws + (size_t)b * M_ * S_;
    float* ob = out + ((size_t)b * NCH_ + 3 + ch) * (size_t)(M_ * S_);
    // 4 elems/thread: int4 idx load + float4 nontemporal store (streamed out)
    for (int e = threadIdx.x * 4; e < M_ * S_; e += 256 * 4) {
        const int4 ii = *(const int4*)(ib + e);
        vf4 w;
        w.x = slice[ii.x]; w.y = slice[ii.y];
        w.z = slice[ii.z]; w.w = slice[ii.w];
        __builtin_nontemporal_store(w, (vf4*)(ob + e));
    }
}

// ---- Fallback: round-1 fused kernel (if ws too small) ----------------------
__global__ __launch_bounds__(256) void qg_fused(
    const float* __restrict__ xyz,
    const float* __restrict__ new_xyz,
    const float* __restrict__ features,
    float* __restrict__ out)
{
    const int bm = blockIdx.x;
    const int b  = bm >> 10;
    const int m  = bm & (M_ - 1);
    const int tid = threadIdx.x;

    __shared__ int s_idx[S_];

    if (tid < 64) {
        const int lane = tid;
        const float cx = new_xyz[bm * 3 + 0];
        const float cy = new_xyz[bm * 3 + 1];
        const float cz = new_xyz[bm * 3 + 2];
        const float r2 = (float)(0.3 * 0.3);
        const float* xb = xyz + (size_t)b * N_ * 3;

        int cnt = 0;
        for (int base = 0; base < N_; base += 64) {
            const int n = base + lane;
            bool valid = false;
            if (n < N_) {
                const float dx = __fadd_rn(xb[n * 3 + 0], -cx);
                const float dy = __fadd_rn(xb[n * 3 + 1], -cy);
                const float dz = __fadd_rn(xb[n * 3 + 2], -cz);
                const float d2 = __fadd_rn(
                    __fadd_rn(__fmul_rn(dx, dx), __fmul_rn(dy, dy)),
                    __fmul_rn(dz, dz));
                valid = d2 < r2;
            }
            const unsigned long long mk = __ballot(valid);
            if (valid) {
                const int pos = cnt + __popcll(mk & ((1ull << lane) - 1ull));
                if (pos < S_) s_idx[pos] = n;
            }
            cnt += __popcll(mk);
            if (cnt >= S_) break;
        }
        const int c = cnt < S_ ? cnt : S_;
        const int first = (c > 0) ? s_idx[0] : 0;
        if (lane >= c) s_idx[lane] = first;

        float* out_idx = out + (size_t)B_ * NCH_ * M_ * S_;
        out_idx[(size_t)bm * S_ + lane] = (float)s_idx[lane];
    }
    __syncthreads();

    if (tid < 3 * S_) {
        const int ch = tid >> 6;
        const int s  = tid & 63;
        const int n  = s_idx[s];
        const float v = (xyz[((size_t)b * N_ + n) * 3 + ch] - new_xyz[bm * 3 + ch]) / 0.3f;
        out[(((size_t)b * NCH_ + ch) * M_ + m) * S_ + s] = v;
    }

    const int s  = tid & 63;
    const int cq = tid >> 6;
    const int n  = s_idx[s];
    const float* fb = features + (size_t)b * C_ * N_;
    float* ob = out + (((size_t)b * NCH_ + 3) * M_ + m) * S_ + s;
    for (int ch = cq; ch < C_; ch += 4) {
        ob[(size_t)ch * (M_ * S_)] = fb[(size_t)ch * N_ + n];
    }
}

extern "C" void kernel_launch(void* const* d_in, const int* in_sizes, int n_in,
                              void* d_out, int out_size, void* d_ws, size_t ws_size,
                              hipStream_t stream) {
    const float* xyz      = (const float*)d_in[0];
    const float* new_xyz  = (const float*)d_in[1];
    // d_in[2] = batch_distances, d_in[3] = inds : acceleration hints only, unused
    const float* features = (const float*)d_in[4];
    float* out = (float*)d_out;

    const size_t need = (size_t)B_ * M_ * S_ * sizeof(int);  // 2 MB
    if (ws_size < need) {
        qg_fused<<<B_ * M_, 256, 0, stream>>>(xyz, new_xyz, features, out);
        return;
    }
    int* iws = (int*)d_ws;

    query_kernel<<<B_ * M_, 256, 0, stream>>>(xyz, new_xyz, out, iws);
    group_feat_kernel<<<B_ * C_, 256, 0, stream>>>(features, iws, out);
}

// Round 10
// 140.717 us; speedup vs baseline: 1.0435x; 1.0435x over previous
//
#include <hip/hip_runtime.h>

#define B_ 8
#define N_ 20000
#define M_ 1024
#define C_ 128
#define S_ 64
#define NCH_ 131    // 3 + C
#define P0_ 10240   // points staged in LDS (120 KB)
#define NG0_ (P0_ / 256)                 // 40 LDS-phase groups
#define NGT_ ((N_ - P0_ + 255) / 256)    // 39 tail groups (global)

typedef float  vf4 __attribute__((ext_vector_type(4)));  // nontemporal-compatible 16B

// ---- K1: ball query; stage-once LDS + barrier-free per-wave scan -----------
// 256 blocks (1 per CU), 1024 threads = 16 waves; each wave owns 2 centers.
__global__ __launch_bounds__(1024) void query_kernel(
    const float* __restrict__ xyz,       // (B, N, 3)
    const float* __restrict__ new_xyz,   // (B, M, 3)
    float* __restrict__ out,
    int* __restrict__ iws)               // (B, M, S) int scratch
{
    const int tid  = threadIdx.x;
    const int w    = tid >> 6;           // wave 0..15
    const int lane = tid & 63;
    const int bm0  = blockIdx.x * 32;    // 32 consecutive centers per block
    const int b    = bm0 >> 10;          // same batch for all 32 (32 | 1024)

    __shared__ __align__(16) float s_pts[P0_ * 3];   // 122880 B
    __shared__ int s_widx[16][S_];                   // 4 KB, per-wave private

    // stage first P0_ points of batch b, coalesced, once
    {
        const float4* g4 = (const float4*)xyz;
        const int base4 = b * ((N_ * 3) / 4);        // 15000 float4 per batch
        float4* s4 = (float4*)s_pts;
        for (int i = tid; i < (P0_ * 3) / 4; i += 1024)
            s4[i] = g4[base4 + i];
    }
    __syncthreads();                     // the ONLY block barrier

    const float* xb = xyz + (size_t)b * N_ * 3;
    const unsigned long long below = (1ull << lane) - 1ull;
    const float r2 = (float)(0.3 * 0.3);

    for (int rep = 0; rep < 2; ++rep) {
        const int bm = bm0 + rep * 16 + w;
        const int m  = bm & (M_ - 1);
        const float cx = new_xyz[bm * 3 + 0];
        const float cy = new_xyz[bm * 3 + 1];
        const float cz = new_xyz[bm * 3 + 2];

        int cnt = 0;

        // ---- phase 1: LDS-resident points [0, P0_), 256 pts/group ----
        for (int g = 0; g < NG0_ && cnt < S_; ++g) {
            unsigned vbits = 0;
            unsigned long long mk[4];
#pragma unroll
            for (int j = 0; j < 4; ++j) {
                const int n = g * 256 + j * 64 + lane;
                const float* pp = s_pts + 3 * n;   // lane stride 12B: 2-way, free
                // match numpy f32 rounding exactly: no FMA contraction
                const float dx = __fadd_rn(pp[0], -cx);
                const float dy = __fadd_rn(pp[1], -cy);
                const float dz = __fadd_rn(pp[2], -cz);
                const float d2 = __fadd_rn(
                    __fadd_rn(__fmul_rn(dx, dx), __fmul_rn(dy, dy)),
                    __fmul_rn(dz, dz));
                const bool valid = d2 < r2;
                mk[j] = __ballot(valid);
                if (valid) vbits |= (1u << j);
            }
            int jbase = cnt;
#pragma unroll
            for (int j = 0; j < 4; ++j) {
                if (vbits & (1u << j)) {
                    const int pos = jbase + __popcll(mk[j] & below);
                    if (pos < S_) s_widx[w][pos] = g * 256 + j * 64 + lane;
                }
                jbase += __popcll(mk[j]);
            }
            cnt = jbase;
        }

        // ---- phase 2: global tail [P0_, N_) (~5% of centers reach here) ----
        for (int g = 0; g < NGT_ && cnt < S_; ++g) {
            unsigned vbits = 0;
            unsigned long long mk[4];
#pragma unroll
            for (int j = 0; j < 4; ++j) {
                const int n = P0_ + g * 256 + j * 64 + lane;
                bool valid = false;
                if (n < N_) {
                    const float* pp = xb + (size_t)n * 3;   // L2-resident
                    const float dx = __fadd_rn(pp[0], -cx);
                    const float dy = __fadd_rn(pp[1], -cy);
                    const float dz = __fadd_rn(pp[2], -cz);
                    const float d2 = __fadd_rn(
                        __fadd_rn(__fmul_rn(dx, dx), __fmul_rn(dy, dy)),
                        __fmul_rn(dz, dz));
                    valid = d2 < r2;
                }
                mk[j] = __ballot(valid);
                if (valid) vbits |= (1u << j);
            }
            int jbase = cnt;
#pragma unroll
            for (int j = 0; j < 4; ++j) {
                if (vbits & (1u << j)) {
                    const int pos = jbase + __popcll(mk[j] & below);
                    if (pos < S_) s_widx[w][pos] = P0_ + g * 256 + j * 64 + lane;
                }
                jbase += __popcll(mk[j]);
            }
            cnt = jbase;
        }

        // pad slots beyond cnt with first valid index (0 if none)
        {
            const int c = cnt < S_ ? cnt : S_;
            const int first = (c > 0) ? s_widx[w][0] : 0;
            if (lane >= c) s_widx[w][lane] = first;
        }

        const int n = s_widx[w][lane];

        // idx outputs (float copy in d_out, int copy for K2 -- keep iws L2-hot)
        float* out_idx = out + (size_t)B_ * NCH_ * M_ * S_;
        __builtin_nontemporal_store((float)n, &out_idx[(size_t)bm * S_ + lane]);
        iws[(size_t)bm * S_ + lane] = n;

        // grouped relative xyz -> channels 0..2 (xyz L2-hot)
        const float px = xb[n * 3 + 0];
        const float py = xb[n * 3 + 1];
        const float pz = xb[n * 3 + 2];
        __builtin_nontemporal_store((px - cx) / 0.3f,
            &out[(((size_t)b * NCH_ + 0) * M_ + m) * S_ + lane]);
        __builtin_nontemporal_store((py - cy) / 0.3f,
            &out[(((size_t)b * NCH_ + 1) * M_ + m) * S_ + lane]);
        __builtin_nontemporal_store((pz - cz) / 0.3f,
            &out[(((size_t)b * NCH_ + 2) * M_ + m) * S_ + lane]);
    }
}

// ---- K2: per (b,ch) block -- stage 80KB channel slice in LDS, gather-write -
__global__ __launch_bounds__(256) void group_feat_kernel(
    const float* __restrict__ features,  // (B, C, N)
    const int* __restrict__ iws,         // (B, M, S)
    float* __restrict__ out)
{
    // b = blockIdx & 7: round-robin dispatch pins each batch to one XCD,
    // keeping that batch's idx slice (256 KB) L2-resident.
    const int b  = blockIdx.x & 7;
    const int ch = blockIdx.x >> 3;

    __shared__ float slice[N_];          // 80000 B (gfx950: >64KB LDS ok)

    const float* fb = features + ((size_t)b * C_ + ch) * N_;
    const vf4* fb4 = (const vf4*)fb;
    vf4* sl4 = (vf4*)slice;
    for (int i = threadIdx.x; i < N_ / 4; i += 256)
        sl4[i] = __builtin_nontemporal_load(&fb4[i]);  // read-once stream
    __syncthreads();

    const int* ib = iws + (size_t)b * M_ * S_;
    float* ob = out + ((size_t)b * NCH_ + 3 + ch) * (size_t)(M_ * S_);
    // 4 elems/thread: int4 idx load + float4 nontemporal store (streamed out)
    for (int e = threadIdx.x * 4; e < M_ * S_; e += 256 * 4) {
        const int4 ii = *(const int4*)(ib + e);
        vf4 w;
        w.x = slice[ii.x]; w.y = slice[ii.y];
        w.z = slice[ii.z]; w.w = slice[ii.w];
        __builtin_nontemporal_store(w, (vf4*)(ob + e));
    }
}

// ---- Fallback: round-1 fused kernel (if ws too small) ----------------------
__global__ __launch_bounds__(256) void qg_fused(
    const float* __restrict__ xyz,
    const float* __restrict__ new_xyz,
    const float* __restrict__ features,
    float* __restrict__ out)
{
    const int bm = blockIdx.x;
    const int b  = bm >> 10;
    const int m  = bm & (M_ - 1);
    const int tid = threadIdx.x;

    __shared__ int s_idx[S_];

    if (tid < 64) {
        const int lane = tid;
        const float cx = new_xyz[bm * 3 + 0];
        const float cy = new_xyz[bm * 3 + 1];
        const float cz = new_xyz[bm * 3 + 2];
        const float r2 = (float)(0.3 * 0.3);
        const float* xb = xyz + (size_t)b * N_ * 3;

        int cnt = 0;
        for (int base = 0; base < N_; base += 64) {
            const int n = base + lane;
            bool valid = false;
            if (n < N_) {
                const float dx = __fadd_rn(xb[n * 3 + 0], -cx);
                const float dy = __fadd_rn(xb[n * 3 + 1], -cy);
                const float dz = __fadd_rn(xb[n * 3 + 2], -cz);
                const float d2 = __fadd_rn(
                    __fadd_rn(__fmul_rn(dx, dx), __fmul_rn(dy, dy)),
                    __fmul_rn(dz, dz));
                valid = d2 < r2;
            }
            const unsigned long long mk = __ballot(valid);
            if (valid) {
                const int pos = cnt + __popcll(mk & ((1ull << lane) - 1ull));
                if (pos < S_) s_idx[pos] = n;
            }
            cnt += __popcll(mk);
            if (cnt >= S_) break;
        }
        const int c = cnt < S_ ? cnt : S_;
        const int first = (c > 0) ? s_idx[0] : 0;
        if (lane >= c) s_idx[lane] = first;

        float* out_idx = out + (size_t)B_ * NCH_ * M_ * S_;
        out_idx[(size_t)bm * S_ + lane] = (float)s_idx[lane];
    }
    __syncthreads();

    if (tid < 3 * S_) {
        const int ch = tid >> 6;
        const int s  = tid & 63;
        const int n  = s_idx[s];
        const float v = (xyz[((size_t)b * N_ + n) * 3 + ch] - new_xyz[bm * 3 + ch]) / 0.3f;
        out[(((size_t)b * NCH_ + ch) * M_ + m) * S_ + s] = v;
    }

    const int s  = tid & 63;
    const int cq = tid >> 6;
    const int n  = s_idx[s];
    const float* fb = features + (size_t)b * C_ * N_;
    float* ob = out + (((size_t)b * NCH_ + 3) * M_ + m) * S_ + s;
    for (int ch = cq; ch < C_; ch += 4) {
        ob[(size_t)ch * (M_ * S_)] = fb[(size_t)ch * N_ + n];
    }
}

extern "C" void kernel_launch(void* const* d_in, const int* in_sizes, int n_in,
                              void* d_out, int out_size, void* d_ws, size_t ws_size,
                              hipStream_t stream) {
    const float* xyz      = (const float*)d_in[0];
    const float* new_xyz  = (const float*)d_in[1];
    // d_in[2] = batch_distances, d_in[3] = inds : acceleration hints only, unused
    const float* features = (const float*)d_in[4];
    float* out = (float*)d_out;

    const size_t need = (size_t)B_ * M_ * S_ * sizeof(int);  // 2 MB
    if (ws_size < need) {
        qg_fused<<<B_ * M_, 256, 0, stream>>>(xyz, new_xyz, features, out);
        return;
    }
    int* iws = (int*)d_ws;

    query_kernel<<<(B_ * M_) / 32, 1024, 0, stream>>>(xyz, new_xyz, out, iws);
    group_feat_kernel<<<B_ * C_, 256, 0, stream>>>(features, iws, out);
}

// Round 11
// 136.656 us; speedup vs baseline: 1.0745x; 1.0297x over previous
//
#include <hip/hip_runtime.h>

#define B_ 8
#define N_ 20000
#define M_ 1024
#define C_ 128
#define S_ 64
#define NCH_ 131    // 3 + C
#define GD_ 7       // grid cells per axis
#define NC_ (GD_*GD_*GD_)   // 343 cells
#define SCALE_ 3.2f // bin width 0.3125 > r=0.3  -> +/-1 cell guarantee strict
#define NW_ 626     // u32 bitmap words per center (20000/32 = 625, +1 pad)
#define NWP_ 640    // padded per-wave bitmap stride

typedef float  vf4 __attribute__((ext_vector_type(4)));  // nontemporal-compatible 16B

__device__ __forceinline__ int cell_of(float x, float y, float z) {
    // x,y,z in [0,2): indices 0..6, monotone binning, same fn for points+centers
    const int ix = (int)(x * SCALE_);
    const int iy = (int)(y * SCALE_);
    const int iz = (int)(z * SCALE_);
    return (ix * GD_ + iy) * GD_ + iz;
}

// ---- K0: bucket points by cell (per batch): counts -> prefix -> scatter ----
__global__ __launch_bounds__(1024) void build_grid(
    const float* __restrict__ xyz,   // (B, N, 3)
    float4* __restrict__ pts4,       // (B, N) packed (x,y,z,orig_idx)
    int* __restrict__ cst)           // (B, 344) cell starts
{
    const int b   = blockIdx.x;
    const int tid = threadIdx.x;
    __shared__ int hcnt[NC_];
    __shared__ int hstart[NC_ + 1];

    if (tid < NC_) hcnt[tid] = 0;
    __syncthreads();

    const float* xb = xyz + (size_t)b * N_ * 3;
    for (int i = tid; i < N_; i += 1024) {
        const float x = xb[3*i], y = xb[3*i+1], z = xb[3*i+2];
        atomicAdd(&hcnt[cell_of(x, y, z)], 1);
    }
    __syncthreads();

    if (tid == 0) {
        int run = 0;
        for (int c = 0; c < NC_; ++c) { hstart[c] = run; run += hcnt[c]; }
        hstart[NC_] = run;   // == N_
    }
    __syncthreads();

    if (tid < NC_ + 1) cst[b * (NC_ + 1) + tid] = hstart[tid];
    if (tid < NC_) hcnt[tid] = hstart[tid];   // write cursors
    __syncthreads();

    for (int i = tid; i < N_; i += 1024) {
        const float x = xb[3*i], y = xb[3*i+1], z = xb[3*i+2];
        const int slot = atomicAdd(&hcnt[cell_of(x, y, z)], 1);
        float4 p; p.x = x; p.y = y; p.z = z; p.w = __int_as_float(i);
        pts4[(size_t)b * N_ + slot] = p;
    }
}

// ---- K1: ball query via grid + per-wave LDS hit-bitmap ---------------------
// 1024 blocks x 512 threads (8 waves); wave = one center.
__global__ __launch_bounds__(512) void query_kernel(
    const float* __restrict__ xyz,       // (B, N, 3) for grouped-xyz output
    const float* __restrict__ new_xyz,   // (B, M, 3)
    const float4* __restrict__ pts4,     // (B, N) cell-sorted
    const int* __restrict__ cst,         // (B, 344)
    float* __restrict__ out,
    int* __restrict__ iws)               // (B, M, S)
{
    const int tid  = threadIdx.x;
    const int w    = tid >> 6;
    const int lane = tid & 63;
    const int bm   = blockIdx.x * 8 + w;
    const int b    = bm >> 10;
    const int m    = bm & (M_ - 1);

    __shared__ unsigned bmap[8][NWP_];   // 8 x 2560 B wave-private bitmaps
    __shared__ int s_widx[8][S_];

    // zero own bitmap (wave-private, no barrier needed)
    for (int k = lane; k < NWP_; k += 64) bmap[w][k] = 0u;

    const float cx = new_xyz[bm * 3 + 0];
    const float cy = new_xyz[bm * 3 + 1];
    const float cz = new_xyz[bm * 3 + 2];
    const float r2 = (float)(0.3 * 0.3);

    const int ix = (int)(cx * SCALE_);
    const int iy = (int)(cy * SCALE_);
    const int iz = (int)(cz * SCALE_);
    const int x0 = ix > 0 ? ix - 1 : 0, x1 = ix < GD_-1 ? ix + 1 : GD_-1;
    const int y0 = iy > 0 ? iy - 1 : 0, y1 = iy < GD_-1 ? iy + 1 : GD_-1;
    const int z0 = iz > 0 ? iz - 1 : 0, z1 = iz < GD_-1 ? iz + 1 : GD_-1;

    const float4* pb = pts4 + (size_t)b * N_;
    const int* cb = cst + b * (NC_ + 1);

    // mark phase: test points of <=27 neighbor cells (z-run contiguous)
    for (int xx = x0; xx <= x1; ++xx) {
        for (int yy = y0; yy <= y1; ++yy) {
            const int cid = (xx * GD_ + yy) * GD_;
            const int s = cb[cid + z0];
            const int e = cb[cid + z1 + 1];
            for (int i = s + lane; i < e; i += 64) {
                const float4 p = pb[i];
                // match numpy f32 rounding exactly: no FMA contraction
                const float dx = __fadd_rn(p.x, -cx);
                const float dy = __fadd_rn(p.y, -cy);
                const float dz = __fadd_rn(p.z, -cz);
                const float d2 = __fadd_rn(
                    __fadd_rn(__fmul_rn(dx, dx), __fmul_rn(dy, dy)),
                    __fmul_rn(dz, dz));
                if (d2 < r2) {
                    const int po = __float_as_int(p.w);
                    atomicOr(&bmap[w][po >> 5], 1u << (po & 31));
                }
            }
        }
    }

    // extract phase: first 64 set bits ascending (== first 64 indices in order)
    int cnt = 0;
    for (int base = 0; base < NW_ && cnt < S_; base += 64) {
        const int wi = base + lane;
        const unsigned wv = (wi < NW_) ? bmap[w][wi] : 0u;
        const int c = __popc(wv);
        int p = c;
#pragma unroll
        for (int o = 1; o < 64; o <<= 1) {
            const int t = __shfl_up(p, o);
            if (lane >= o) p += t;
        }
        const int tot = __shfl(p, 63);
        int r = cnt + p - c;             // exclusive prefix rank
        unsigned ww = wv;
        while (ww && r < S_) {
            const int bit = __ffs(ww) - 1;
            s_widx[w][r] = wi * 32 + bit;
            ++r;
            ww &= ww - 1;
        }
        cnt += tot;
    }

    // pad slots beyond cnt with first valid index (0 if none)
    {
        const int c = cnt < S_ ? cnt : S_;
        const int first = (c > 0) ? s_widx[w][0] : 0;
        if (lane >= c) s_widx[w][lane] = first;
    }

    const int n = s_widx[w][lane];
    const float* xb = xyz + (size_t)b * N_ * 3;

    // idx outputs (float copy in d_out, int copy for K2 -- keep iws L2-hot)
    float* out_idx = out + (size_t)B_ * NCH_ * M_ * S_;
    __builtin_nontemporal_store((float)n, &out_idx[(size_t)bm * S_ + lane]);
    iws[(size_t)bm * S_ + lane] = n;

    // grouped relative xyz -> channels 0..2 (xyz slice L2-hot)
    const float px = xb[n * 3 + 0];
    const float py = xb[n * 3 + 1];
    const float pz = xb[n * 3 + 2];
    __builtin_nontemporal_store((px - cx) / 0.3f,
        &out[(((size_t)b * NCH_ + 0) * M_ + m) * S_ + lane]);
    __builtin_nontemporal_store((py - cy) / 0.3f,
        &out[(((size_t)b * NCH_ + 1) * M_ + m) * S_ + lane]);
    __builtin_nontemporal_store((pz - cz) / 0.3f,
        &out[(((size_t)b * NCH_ + 2) * M_ + m) * S_ + lane]);
}

// ---- K2: per (b,ch) block -- stage 80KB channel slice in LDS, gather-write -
__global__ __launch_bounds__(256) void group_feat_kernel(
    const float* __restrict__ features,  // (B, C, N)
    const int* __restrict__ iws,         // (B, M, S)
    float* __restrict__ out)
{
    // b = blockIdx & 7: round-robin dispatch pins each batch to one XCD,
    // keeping that batch's idx slice (256 KB) L2-resident.
    const int b  = blockIdx.x & 7;
    const int ch = blockIdx.x >> 3;

    __shared__ float slice[N_];          // 80000 B (gfx950: >64KB LDS ok)

    const float* fb = features + ((size_t)b * C_ + ch) * N_;
    const vf4* fb4 = (const vf4*)fb;
    vf4* sl4 = (vf4*)slice;
    for (int i = threadIdx.x; i < N_ / 4; i += 256)
        sl4[i] = __builtin_nontemporal_load(&fb4[i]);  // read-once stream
    __syncthreads();

    const int* ib = iws + (size_t)b * M_ * S_;
    float* ob = out + ((size_t)b * NCH_ + 3 + ch) * (size_t)(M_ * S_);
    // 4 elems/thread: int4 idx load + float4 nontemporal store (streamed out)
    for (int e = threadIdx.x * 4; e < M_ * S_; e += 256 * 4) {
        const int4 ii = *(const int4*)(ib + e);
        vf4 w;
        w.x = slice[ii.x]; w.y = slice[ii.y];
        w.z = slice[ii.z]; w.w = slice[ii.w];
        __builtin_nontemporal_store(w, (vf4*)(ob + e));
    }
}

// ---- Fallback: round-1 fused kernel (if ws too small) ----------------------
__global__ __launch_bounds__(256) void qg_fused(
    const float* __restrict__ xyz,
    const float* __restrict__ new_xyz,
    const float* __restrict__ features,
    float* __restrict__ out)
{
    const int bm = blockIdx.x;
    const int b  = bm >> 10;
    const int m  = bm & (M_ - 1);
    const int tid = threadIdx.x;

    __shared__ int s_idx[S_];

    if (tid < 64) {
        const int lane = tid;
        const float cx = new_xyz[bm * 3 + 0];
        const float cy = new_xyz[bm * 3 + 1];
        const float cz = new_xyz[bm * 3 + 2];
        const float r2 = (float)(0.3 * 0.3);
        const float* xb = xyz + (size_t)b * N_ * 3;

        int cnt = 0;
        for (int base = 0; base < N_; base += 64) {
            const int n = base + lane;
            bool valid = false;
            if (n < N_) {
                const float dx = __fadd_rn(xb[n * 3 + 0], -cx);
                const float dy = __fadd_rn(xb[n * 3 + 1], -cy);
                const float dz = __fadd_rn(xb[n * 3 + 2], -cz);
                const float d2 = __fadd_rn(
                    __fadd_rn(__fmul_rn(dx, dx), __fmul_rn(dy, dy)),
                    __fmul_rn(dz, dz));
                valid = d2 < r2;
            }
            const unsigned long long mk = __ballot(valid);
            if (valid) {
                const int pos = cnt + __popcll(mk & ((1ull << lane) - 1ull));
                if (pos < S_) s_idx[pos] = n;
            }
            cnt += __popcll(mk);
            if (cnt >= S_) break;
        }
        const int c = cnt < S_ ? cnt : S_;
        const int first = (c > 0) ? s_idx[0] : 0;
        if (lane >= c) s_idx[lane] = first;

        float* out_idx = out + (size_t)B_ * NCH_ * M_ * S_;
        out_idx[(size_t)bm * S_ + lane] = (float)s_idx[lane];
    }
    __syncthreads();

    if (tid < 3 * S_) {
        const int ch = tid >> 6;
        const int s  = tid & 63;
        const int n  = s_idx[s];
        const float v = (xyz[((size_t)b * N_ + n) * 3 + ch] - new_xyz[bm * 3 + ch]) / 0.3f;
        out[(((size_t)b * NCH_ + ch) * M_ + m) * S_ + s] = v;
    }

    const int s  = tid & 63;
    const int cq = tid >> 6;
    const int n  = s_idx[s];
    const float* fb = features + (size_t)b * C_ * N_;
    float* ob = out + (((size_t)b * NCH_ + 3) * M_ + m) * S_ + s;
    for (int ch = cq; ch < C_; ch += 4) {
        ob[(size_t)ch * (M_ * S_)] = fb[(size_t)ch * N_ + n];
    }
}

extern "C" void kernel_launch(void* const* d_in, const int* in_sizes, int n_in,
                              void* d_out, int out_size, void* d_ws, size_t ws_size,
                              hipStream_t stream) {
    const float* xyz      = (const float*)d_in[0];
    const float* new_xyz  = (const float*)d_in[1];
    // d_in[2] = batch_distances, d_in[3] = inds : acceleration hints only, unused
    const float* features = (const float*)d_in[4];
    float* out = (float*)d_out;

    // ws layout: pts4 (B*N float4) | cst (B*344 int) | iws (B*M*S int)
    const size_t pts4_elems = (size_t)B_ * N_;
    const size_t cst_elems  = (size_t)B_ * (NC_ + 1);
    const size_t iws_elems  = (size_t)B_ * M_ * S_;
    const size_t need = pts4_elems * 16 + (cst_elems + iws_elems) * 4;

    if (ws_size < need) {
        qg_fused<<<B_ * M_, 256, 0, stream>>>(xyz, new_xyz, features, out);
        return;
    }
    float4* pts4 = (float4*)d_ws;
    int*    cst  = (int*)(pts4 + pts4_elems);
    int*    iws  = cst + cst_elems;

    build_grid<<<B_, 1024, 0, stream>>>(xyz, pts4, cst);
    query_kernel<<<(B_ * M_) / 8, 512, 0, stream>>>(xyz, new_xyz, pts4, cst, out, iws);
    group_feat_kernel<<<B_ * C_, 256, 0, stream>>>(features, iws, out);
}